// Round 2
// baseline (428.363 us; speedup 1.0000x reference)
//
#include <hip/hip_runtime.h>

// Problem constants
#define DD 128    // nodes / input dim
#define HH 512    // hidden
#define NN 2048   // batch rows
#define NT 64     // rows per block tile
#define PLD 516   // pack LDS leading dim

typedef __bf16 bf16x8 __attribute__((ext_vector_type(8)));
typedef __bf16 bf16x4 __attribute__((ext_vector_type(4)));
typedef float  floatx4 __attribute__((ext_vector_type(4)));

// ---------------------------------------------------------------------------
// x (fp32 row-major) -> xb (bf16 row-major). 2048x128, 16B/thread.
// ---------------------------------------------------------------------------
__global__ void cvt_x(const float* __restrict__ x, __bf16* __restrict__ xb) {
    int t = blockIdx.x * blockDim.x + threadIdx.x;
    float4 v = *(const float4*)(x + (size_t)t * 4);
    bf16x4 o;
    o[0] = (__bf16)v.x; o[1] = (__bf16)v.y; o[2] = (__bf16)v.z; o[3] = (__bf16)v.w;
    *(bf16x4*)(xb + (size_t)t * 4) = o;
}

// ---------------------------------------------------------------------------
// Pack W[d][K][H] fp32 -> bf16 MFMA fragment order via LDS transpose.
//   Wp[((((d*32+ct)*nks+ks)*4+q)*16+c)*8+j] = bf16(W[d][ks*32+q*8+j][ct*16+c])
// ---------------------------------------------------------------------------
__global__ void pack_w(const float* __restrict__ W, __bf16* __restrict__ Wp, int nks) {
    __shared__ __bf16 Ls[32 * PLD];
    const int d  = blockIdx.x / nks;
    const int ks = blockIdx.x % nks;
    const int tid = threadIdx.x;
    const float* src = W + ((size_t)(d * nks + ks) * 32) * HH;

#pragma unroll
    for (int it = 0; it < 16; ++it) {
        int e = (it * 256 + tid) * 4;
        float4 v = *(const float4*)(src + e);
        bf16x4 o;
        o[0] = (__bf16)v.x; o[1] = (__bf16)v.y; o[2] = (__bf16)v.z; o[3] = (__bf16)v.w;
        *(bf16x4*)(Ls + (e >> 9) * PLD + (e & 511)) = o;
    }
    __syncthreads();

#pragma unroll
    for (int it = 0; it < 8; ++it) {
        int ch = it * 256 + tid;
        int c  = ch & 15;
        int q  = (ch >> 4) & 3;
        int ct = ch >> 6;
        bf16x8 v;
#pragma unroll
        for (int j = 0; j < 8; ++j)
            v[j] = Ls[(q * 8 + j) * PLD + ct * 16 + c];
        *(bf16x8*)(Wp + ((size_t)(d * 32 + ct) * nks + ks) * 512 + (ch & 63) * 8) = v;
    }
}

// ---------------------------------------------------------------------------
// Fused per-(d, row-tile) MLP, transposed operand order:
//   mfma(Wfrag, Xfrag) => D = (X.W)^T: lane lc holds output ROW lc.
// NT=64 (r1 showed occupancy > traffic). This round:
//  - explicit wf double-buffer (next-ks W frags loaded during current MFMAs)
//    -> removes the per-ks vmcnt(0) L2-latency drain; launch_bounds(512,3)
//    gives the allocator headroom (~170 regs) for the prefetch registers.
//  - readfirstlane(w): wave-uniform address math goes to SALU (VALUBusy cut).
//  - setprio(1) around pure-MFMA clusters (waves are barrier-free in ph2).
//  - atomic-free phase-3 cross-wave reduce via outp2[8][NT].
// ---------------------------------------------------------------------------
__launch_bounds__(512, 3)
__global__ void grandag_main(const __bf16* __restrict__ xb,
                             const __bf16* __restrict__ W0p,
                             const __bf16* __restrict__ W1p,
                             const float* __restrict__ W2,
                             float* __restrict__ out) {
    __shared__ __bf16 h1s[NT * HH];      // 65536 B
    __shared__ float  outp2[8][NT];      // 2048 B -> 67.5KB total, 2 blocks/CU

    const int b  = blockIdx.x;
    // XCD swizzle: d % 8 == blockIdx % 8 -> all 32 tiles of a d on one XCD
    const int d  = ((b >> 8) << 3) | (b & 7);
    const int n0 = ((b >> 3) & 31) * NT;

    const int tid = threadIdx.x;
    const int w   = __builtin_amdgcn_readfirstlane(tid >> 6);  // wave id: SGPR
    const int l   = tid & 63;
    const int lc  = l & 15;     // C/D col = batch row (transposed form)
    const int lq  = l >> 4;     // k-quad
    const int sw  = lc & 7;     // LDS swizzle key (row-derived)
    const int lane16 = lq * 16 + lc;   // per-lane frag index (8-elem units)

    const int ksz = d >> 5;          // k-slice containing column d of X
    const int lqz = (d >> 3) & 3;    // quad containing it
    const int jz  = d & 7;           // element containing it

    // ---- phase 1: acc[mt][nt] = W0[d]^T (cols 64w+16mt..) . Xmask^T (rows 16nt..)
    {
        floatx4 acc[4][4] = {};
        const __bf16* W0b = W0p + ((size_t)(d * 32 + w * 4) * 4) * 512 + (size_t)lane16 * 8;
        const __bf16* xbb = xb + (size_t)(n0 + lc) * DD + lq * 8;
        bf16x8 wf[4], wfn[4];
#pragma unroll
        for (int mt = 0; mt < 4; mt++)
            wf[mt] = *(const bf16x8*)(W0b + (size_t)(mt * 4) * 512);
#pragma unroll
        for (int ks = 0; ks < 4; ks++) {
            const int ksn = (ks + 1) & 3;   // last iter re-loads ks=0 (harmless)
#pragma unroll
            for (int mt = 0; mt < 4; mt++)
                wfn[mt] = *(const bf16x8*)(W0b + (size_t)(mt * 4 + ksn) * 512);
            bf16x8 xf[4];
#pragma unroll
            for (int nt = 0; nt < 4; nt++)
                xf[nt] = *(const bf16x8*)(xbb + (size_t)(16 * nt) * DD + ks * 32);
            if ((ks == ksz) && (lq == lqz)) {
#pragma unroll
                for (int nt = 0; nt < 4; nt++)
#pragma unroll
                    for (int j = 0; j < 8; j++)
                        if (j == jz) xf[nt][j] = (__bf16)0.f;
            }
            __builtin_amdgcn_s_setprio(1);
#pragma unroll
            for (int nt = 0; nt < 4; nt++)
#pragma unroll
                for (int mt = 0; mt < 4; mt++)
                    acc[mt][nt] = __builtin_amdgcn_mfma_f32_16x16x32_bf16(
                        wf[mt], xf[nt], acc[mt][nt], 0, 0, 0);
            __builtin_amdgcn_s_setprio(0);
#pragma unroll
            for (int mt = 0; mt < 4; mt++) wf[mt] = wfn[mt];
        }
        // epilogue: lane holds h1[row=16nt+lc][col=64w+16mt+4lq+g], g=0..3
        // h1s layout: row-major 512, 16B chunks XOR-swizzled by row&7.
#pragma unroll
        for (int mt = 0; mt < 4; mt++) {
            const int chunk = 8 * w + 2 * mt + (lq >> 1);
#pragma unroll
            for (int nt = 0; nt < 4; nt++) {
                bf16x4 o;
#pragma unroll
                for (int g = 0; g < 4; g++) {
                    float v = acc[mt][nt][g];
                    o[g] = (__bf16)fmaxf(v, 0.01f * v);   // leaky relu
                }
                *(bf16x4*)(h1s + (16 * nt + lc) * HH + ((chunk ^ sw) << 3) + ((lq & 1) << 2)) = o;
            }
        }
    }
    __syncthreads();

    // ---- phase 2: acc2[mt][nt] = W1[d]^T (cols 64w+16mt..) . h1^T (rows 16nt..)
    floatx4 acc2[4][4] = {};
    {
        const __bf16* W1b = W1p + ((size_t)(d * 32 + w * 4) * 16) * 512 + (size_t)lane16 * 8;
        const __bf16* h1b = h1s + lc * HH;
        bf16x8 wf[4], wfn[4];
#pragma unroll
        for (int mt = 0; mt < 4; mt++)
            wf[mt] = *(const bf16x8*)(W1b + (size_t)(mt * 16) * 512);
#pragma unroll 4
        for (int ks = 0; ks < 16; ks++) {
            const int ksn = (ks + 1) & 15;  // last iter re-loads ks=0 (harmless)
#pragma unroll
            for (int mt = 0; mt < 4; mt++)
                wfn[mt] = *(const bf16x8*)(W1b + (size_t)(mt * 16 + ksn) * 512);
            const int hoff = ((4 * ks + lq) ^ sw) << 3;
            bf16x8 hf[4];
#pragma unroll
            for (int nt = 0; nt < 4; nt++)
                hf[nt] = *(const bf16x8*)(h1b + 16 * nt * HH + hoff);
            __builtin_amdgcn_s_setprio(1);
#pragma unroll
            for (int nt = 0; nt < 4; nt++)
#pragma unroll
                for (int mt = 0; mt < 4; mt++)
                    acc2[mt][nt] = __builtin_amdgcn_mfma_f32_16x16x32_bf16(
                        wf[mt], hf[nt], acc2[mt][nt], 0, 0, 0);
            __builtin_amdgcn_s_setprio(0);
#pragma unroll
            for (int mt = 0; mt < 4; mt++) wf[mt] = wfn[mt];
        }
    }

    // ---- phase 3: out = leaky(h2) @ W2[d]; lane lc holds rows 16nt+lc
    {
        const float* W2b = W2 + (size_t)d * HH + w * 64 + lq * 4;
        floatx4 w2q[4];
#pragma unroll
        for (int mt = 0; mt < 4; mt++)
            w2q[mt] = *(const floatx4*)(W2b + mt * 16);
#pragma unroll
        for (int nt = 0; nt < 4; nt++) {
            float s = 0.f;
#pragma unroll
            for (int mt = 0; mt < 4; mt++) {
#pragma unroll
                for (int g = 0; g < 4; g++) {
                    float v = acc2[mt][nt][g];
                    s += fmaxf(v, 0.01f * v) * w2q[mt][g];
                }
            }
            // sum the 4 lq-groups holding the same row
            s += __shfl_xor(s, 16, 64);
            s += __shfl_xor(s, 32, 64);
            if (l < 16) outp2[w][16 * nt + lc] = s;   // per-wave partial, no atomics
        }
    }
    __syncthreads();
    if (tid < NT) {
        float v = 0.f;
#pragma unroll
        for (int ww = 0; ww < 8; ww++) v += outp2[ww][tid];
        out[(size_t)(n0 + tid) * DD + d] = v;
    }
}

// ---------------------------------------------------------------------------
extern "C" void kernel_launch(void* const* d_in, const int* in_sizes, int n_in,
                              void* d_out, int out_size, void* d_ws, size_t ws_size,
                              hipStream_t stream) {
    const float* x  = (const float*)d_in[0];
    const float* W0 = (const float*)d_in[1];
    const float* W1 = (const float*)d_in[2];
    const float* W2 = (const float*)d_in[3];
    float* out = (float*)d_out;

    __bf16* W0p = (__bf16*)d_ws;                                          // 16.8 MB
    __bf16* W1p = (__bf16*)((char*)d_ws + (size_t)DD * DD * HH * 2);      // 67.1 MB
    __bf16* xb  = (__bf16*)((char*)d_ws + (size_t)DD * DD * HH * 2
                                        + (size_t)DD * HH * HH * 2);      // 0.5 MB

    cvt_x<<<dim3(NN * DD / (256 * 4)), 256, 0, stream>>>(x, xb);
    pack_w<<<dim3(DD * (DD / 32)), 256, 0, stream>>>(W0, W0p, DD / 32);   // 512 blocks
    pack_w<<<dim3(DD * (HH / 32)), 256, 0, stream>>>(W1, W1p, HH / 32);   // 2048 blocks

    grandag_main<<<dim3(DD * (NN / NT)), 512, 0, stream>>>(xb, W0p, W1p, W2, out);
}

// Round 3
// 418.935 us; speedup vs baseline: 1.0225x; 1.0225x over previous
//
#include <hip/hip_runtime.h>

// Problem constants
#define DD 128    // nodes / input dim
#define HH 512    // hidden
#define NN 2048   // batch rows
#define NT 64     // rows per block tile
#define PLD 516   // pack LDS leading dim

typedef __bf16 bf16x8 __attribute__((ext_vector_type(8)));
typedef __bf16 bf16x4 __attribute__((ext_vector_type(4)));
typedef float  floatx4  __attribute__((ext_vector_type(4)));
typedef float  floatx16 __attribute__((ext_vector_type(16)));

// ---------------------------------------------------------------------------
// x (fp32 row-major) -> xb (bf16 row-major). 2048x128, 16B/thread.
// ---------------------------------------------------------------------------
__global__ void cvt_x(const float* __restrict__ x, __bf16* __restrict__ xb) {
    int t = blockIdx.x * blockDim.x + threadIdx.x;
    float4 v = *(const float4*)(x + (size_t)t * 4);
    bf16x4 o;
    o[0] = (__bf16)v.x; o[1] = (__bf16)v.y; o[2] = (__bf16)v.z; o[3] = (__bf16)v.w;
    *(bf16x4*)(xb + (size_t)t * 4) = o;
}

// ---------------------------------------------------------------------------
// Pack W[d][K][H] fp32 -> bf16 32x32x16 A-fragment order via LDS transpose.
// Frag layout (A = W^T, m = H-col, k = K-row): lane l holds
//   A[ct*32 + (l&31)][ks*16 + (l>>5)*8 + j],  j = 0..7
//   Wp[((d*16 + ct)*nks16 + ks)*512 + l*8 + j] = W[d][ks*16+(l>>5)*8+j][ct*32+(l&31)]
// One block transposes a 32-K-row x 512-col slab (2 k-steps).
// ---------------------------------------------------------------------------
__global__ void pack_w(const float* __restrict__ W, __bf16* __restrict__ Wp, int nks32) {
    __shared__ __bf16 Ls[32 * PLD];
    const int d  = blockIdx.x / nks32;
    const int ks = blockIdx.x % nks32;      // 32-row slab index
    const int tid = threadIdx.x;
    const int nks16 = nks32 * 2;
    const float* src = W + ((size_t)(d * nks32 + ks) * 32) * HH;

#pragma unroll
    for (int it = 0; it < 16; ++it) {
        int e = (it * 256 + tid) * 4;
        float4 v = *(const float4*)(src + e);
        bf16x4 o;
        o[0] = (__bf16)v.x; o[1] = (__bf16)v.y; o[2] = (__bf16)v.z; o[3] = (__bf16)v.w;
        *(bf16x4*)(Ls + (e >> 9) * PLD + (e & 511)) = o;
    }
    __syncthreads();

#pragma unroll
    for (int it = 0; it < 8; ++it) {
        int u  = it * 256 + tid;            // [0, 2048): 8-elem output units
        int l  = u & 63;
        int ct = (u >> 6) & 15;             // 32-col tile
        int kh = u >> 10;                   // k-substep within slab (0,1)
        int lr = l & 31, lh = l >> 5;
        bf16x8 v;
#pragma unroll
        for (int j = 0; j < 8; ++j)
            v[j] = Ls[(kh * 16 + lh * 8 + j) * PLD + ct * 32 + lr];
        *(bf16x8*)(Wp + ((size_t)(d * 16 + ct) * nks16 + (ks * 2 + kh)) * 512 + l * 8) = v;
    }
}

// ---------------------------------------------------------------------------
// Fused per-(d, row-tile) MLP, 32x32x16 MFMA, transposed operand order:
//   mfma(Wfrag, Xfrag) => D = (X.W)^T: lane (l&31) holds output ROW, D reg g
//   maps to h-col (g&3)+8*(g>>2)+4*(l>>5) within the 32-tile (m74/m101 layout).
// Why 32x32: same FLOPs at the 2382-TF rate (vs 2075), HALF the MFMA instr
// count, and HALF the live fragment regs -> a 1-step ping-pong W-prefetch
// fits inside the 64-VGPR cap (64V + 64 AGPR acc = 128 = 4 waves/SIMD; r2
// proved +4 VGPRs over that halves occupancy).
// ---------------------------------------------------------------------------
__launch_bounds__(512, 4)
__global__ void grandag_main(const __bf16* __restrict__ xb,
                             const __bf16* __restrict__ W0p,
                             const __bf16* __restrict__ W1p,
                             const float* __restrict__ W2,
                             float* __restrict__ out) {
    __shared__ __bf16 h1s[NT * HH];      // 65536 B
    __shared__ float  outp2[8][NT];      // 2048 B: per-wave partials (no atomics)

    const int b  = blockIdx.x;
    // XCD swizzle: d % 8 == blockIdx % 8 -> all 32 tiles of a d on one XCD
    const int d  = ((b >> 8) << 3) | (b & 7);
    const int n0 = ((b >> 3) & 31) * NT;

    const int tid = threadIdx.x;
    const int w   = tid >> 6;   // wave 0..7: owns h-cols [w*64, w*64+64)
    const int l   = tid & 63;
    const int lr  = l & 31;     // C/D col = batch row within 32-tile
    const int lh  = l >> 5;     // k half-group
    const int swz = lr & 7;     // h1s chunk-swizzle key (row-derived)

    const int kz  = d >> 4;          // k-step containing column d of X
    const int lhz = (d >> 3) & 1;    // half-group containing it
    const int jz  = d & 7;           // element containing it

    // ---- phase 1: acc[mt][nt] = W0[d]^T (32-col tiles) . Xmask^T (32-row tiles)
    {
        floatx16 acc[2][2] = {};
        const __bf16* W0b = W0p + ((size_t)(d * 16 + w * 2) * 8) * 512 + (size_t)l * 8;
        const __bf16* xbb = xb + (size_t)(n0 + lr) * DD + lh * 8;

        bf16x8 wa0 = *(const bf16x8*)(W0b);
        bf16x8 wa1 = *(const bf16x8*)(W0b + (size_t)8 * 512);
#pragma unroll
        for (int ks = 0; ks < 8; ks += 2) {
            // prefetch next-step W frags while this step's MFMAs run
            bf16x8 wb0 = *(const bf16x8*)(W0b + (size_t)(ks + 1) * 512);
            bf16x8 wb1 = *(const bf16x8*)(W0b + (size_t)(8 + ks + 1) * 512);
            bf16x8 x0 = *(const bf16x8*)(xbb + (size_t)ks * 16);
            bf16x8 x1 = *(const bf16x8*)(xbb + (size_t)32 * DD + ks * 16);
            if (ks == kz && lh == lhz) {
#pragma unroll
                for (int j = 0; j < 8; j++)
                    if (j == jz) { x0[j] = (__bf16)0.f; x1[j] = (__bf16)0.f; }
            }
            acc[0][0] = __builtin_amdgcn_mfma_f32_32x32x16_bf16(wa0, x0, acc[0][0], 0, 0, 0);
            acc[0][1] = __builtin_amdgcn_mfma_f32_32x32x16_bf16(wa0, x1, acc[0][1], 0, 0, 0);
            acc[1][0] = __builtin_amdgcn_mfma_f32_32x32x16_bf16(wa1, x0, acc[1][0], 0, 0, 0);
            acc[1][1] = __builtin_amdgcn_mfma_f32_32x32x16_bf16(wa1, x1, acc[1][1], 0, 0, 0);
            wa0 = *(const bf16x8*)(W0b + (size_t)((ks + 2) & 7) * 512);
            wa1 = *(const bf16x8*)(W0b + (size_t)(8 + ((ks + 2) & 7)) * 512);
            x0 = *(const bf16x8*)(xbb + (size_t)(ks + 1) * 16);
            x1 = *(const bf16x8*)(xbb + (size_t)32 * DD + (ks + 1) * 16);
            if (ks + 1 == kz && lh == lhz) {
#pragma unroll
                for (int j = 0; j < 8; j++)
                    if (j == jz) { x0[j] = (__bf16)0.f; x1[j] = (__bf16)0.f; }
            }
            acc[0][0] = __builtin_amdgcn_mfma_f32_32x32x16_bf16(wb0, x0, acc[0][0], 0, 0, 0);
            acc[0][1] = __builtin_amdgcn_mfma_f32_32x32x16_bf16(wb0, x1, acc[0][1], 0, 0, 0);
            acc[1][0] = __builtin_amdgcn_mfma_f32_32x32x16_bf16(wb1, x0, acc[1][0], 0, 0, 0);
            acc[1][1] = __builtin_amdgcn_mfma_f32_32x32x16_bf16(wb1, x1, acc[1][1], 0, 0, 0);
        }
        // epilogue: lane holds h1[row = nt*32+lr][hcol = 64w+32mt+8q2+4lh+i]
        // h1s layout: row-major 512, 16B chunks XOR-swizzled by row&7.
#pragma unroll
        for (int mt = 0; mt < 2; mt++) {
#pragma unroll
            for (int q2 = 0; q2 < 4; q2++) {
                const int chunk = 8 * w + 4 * mt + q2;
#pragma unroll
                for (int nt = 0; nt < 2; nt++) {
                    const int row = nt * 32 + lr;
                    bf16x4 o;
#pragma unroll
                    for (int i = 0; i < 4; i++) {
                        float v = acc[mt][nt][q2 * 4 + i];
                        o[i] = (__bf16)fmaxf(v, 0.01f * v);   // leaky relu
                    }
                    *(bf16x4*)(h1s + (size_t)row * HH + ((chunk ^ swz) << 3) + 4 * lh) = o;
                }
            }
        }
    }
    __syncthreads();

    // ---- phase 2: acc2[mt][nt] = W1[d]^T (32-col tiles) . h1^T (32-row tiles)
    floatx16 acc2[2][2] = {};
    {
        const __bf16* W1b  = W1p + ((size_t)(d * 16 + w * 2) * 32) * 512 + (size_t)l * 8;
        const __bf16* h1b0 = h1s + (size_t)lr * HH;          // nt=0 row
        const __bf16* h1b1 = h1s + (size_t)(32 + lr) * HH;   // nt=1 row

        bf16x8 wa0 = *(const bf16x8*)(W1b);
        bf16x8 wa1 = *(const bf16x8*)(W1b + (size_t)32 * 512);
#pragma unroll
        for (int ks = 0; ks < 32; ks += 2) {
            bf16x8 wb0 = *(const bf16x8*)(W1b + (size_t)(ks + 1) * 512);
            bf16x8 wb1 = *(const bf16x8*)(W1b + (size_t)(32 + ks + 1) * 512);
            bf16x8 h0  = *(const bf16x8*)(h1b0 + (((2 * ks + lh) ^ swz) << 3));
            bf16x8 h1v = *(const bf16x8*)(h1b1 + (((2 * ks + lh) ^ swz) << 3));
            acc2[0][0] = __builtin_amdgcn_mfma_f32_32x32x16_bf16(wa0, h0,  acc2[0][0], 0, 0, 0);
            acc2[0][1] = __builtin_amdgcn_mfma_f32_32x32x16_bf16(wa0, h1v, acc2[0][1], 0, 0, 0);
            acc2[1][0] = __builtin_amdgcn_mfma_f32_32x32x16_bf16(wa1, h0,  acc2[1][0], 0, 0, 0);
            acc2[1][1] = __builtin_amdgcn_mfma_f32_32x32x16_bf16(wa1, h1v, acc2[1][1], 0, 0, 0);
            wa0 = *(const bf16x8*)(W1b + (size_t)((ks + 2) & 31) * 512);
            wa1 = *(const bf16x8*)(W1b + (size_t)(32 + ((ks + 2) & 31)) * 512);
            h0  = *(const bf16x8*)(h1b0 + (((2 * (ks + 1) + lh) ^ swz) << 3));
            h1v = *(const bf16x8*)(h1b1 + (((2 * (ks + 1) + lh) ^ swz) << 3));
            acc2[0][0] = __builtin_amdgcn_mfma_f32_32x32x16_bf16(wb0, h0,  acc2[0][0], 0, 0, 0);
            acc2[0][1] = __builtin_amdgcn_mfma_f32_32x32x16_bf16(wb0, h1v, acc2[0][1], 0, 0, 0);
            acc2[1][0] = __builtin_amdgcn_mfma_f32_32x32x16_bf16(wb1, h0,  acc2[1][0], 0, 0, 0);
            acc2[1][1] = __builtin_amdgcn_mfma_f32_32x32x16_bf16(wb1, h1v, acc2[1][1], 0, 0, 0);
        }
    }

    // ---- phase 3: out = leaky(h2) @ W2[d]; lane lr holds rows nt*32+lr
    {
        const float* W2b = W2 + (size_t)d * HH + w * 64 + lh * 4;
#pragma unroll
        for (int nt = 0; nt < 2; nt++) {
            float s = 0.f;
#pragma unroll
            for (int mt = 0; mt < 2; mt++) {
#pragma unroll
                for (int q2 = 0; q2 < 4; q2++) {
                    floatx4 w2q = *(const floatx4*)(W2b + mt * 32 + 8 * q2);
#pragma unroll
                    for (int i = 0; i < 4; i++) {
                        float v = acc2[mt][nt][q2 * 4 + i];
                        s += fmaxf(v, 0.01f * v) * w2q[i];
                    }
                }
            }
            // the lh=1 half holds the other 32 h-cols of this wave
            s += __shfl_xor(s, 32, 64);
            if (!lh) outp2[w][nt * 32 + lr] = s;   // per-wave partial, no atomics
        }
    }
    __syncthreads();
    if (tid < NT) {
        float v = 0.f;
#pragma unroll
        for (int ww = 0; ww < 8; ww++) v += outp2[ww][tid];
        out[(size_t)(n0 + tid) * DD + d] = v;
    }
}

// ---------------------------------------------------------------------------
extern "C" void kernel_launch(void* const* d_in, const int* in_sizes, int n_in,
                              void* d_out, int out_size, void* d_ws, size_t ws_size,
                              hipStream_t stream) {
    const float* x  = (const float*)d_in[0];
    const float* W0 = (const float*)d_in[1];
    const float* W1 = (const float*)d_in[2];
    const float* W2 = (const float*)d_in[3];
    float* out = (float*)d_out;

    __bf16* W0p = (__bf16*)d_ws;                                          // 16.8 MB
    __bf16* W1p = (__bf16*)((char*)d_ws + (size_t)DD * DD * HH * 2);      // 67.1 MB
    __bf16* xb  = (__bf16*)((char*)d_ws + (size_t)DD * DD * HH * 2
                                        + (size_t)DD * HH * HH * 2);      // 0.5 MB

    cvt_x<<<dim3(NN * DD / (256 * 4)), 256, 0, stream>>>(x, xb);
    pack_w<<<dim3(DD * (DD / 32)), 256, 0, stream>>>(W0, W0p, DD / 32);   // 512 blocks
    pack_w<<<dim3(DD * (HH / 32)), 256, 0, stream>>>(W1, W1p, HH / 32);   // 2048 blocks

    grandag_main<<<dim3(DD * (NN / NT)), 512, 0, stream>>>(xb, W0p, W1p, W2, out);
}

// Round 4
// 418.715 us; speedup vs baseline: 1.0230x; 1.0005x over previous
//
#include <hip/hip_runtime.h>

// Problem constants
#define DD 128    // nodes / input dim
#define HH 512    // hidden
#define NN 2048   // batch rows
#define NT 64     // rows per block tile
#define PLD 516   // pack LDS leading dim

typedef __bf16 bf16x8 __attribute__((ext_vector_type(8)));
typedef __bf16 bf16x4 __attribute__((ext_vector_type(4)));
typedef float  floatx4  __attribute__((ext_vector_type(4)));
typedef float  floatx16 __attribute__((ext_vector_type(16)));

typedef const __attribute__((address_space(1))) void* as1cv;
typedef __attribute__((address_space(3))) void* as3v;

// ---------------------------------------------------------------------------
// x (fp32 row-major) -> xb (bf16 row-major). 2048x128, 16B/thread.
// ---------------------------------------------------------------------------
__global__ void cvt_x(const float* __restrict__ x, __bf16* __restrict__ xb) {
    int t = blockIdx.x * blockDim.x + threadIdx.x;
    float4 v = *(const float4*)(x + (size_t)t * 4);
    bf16x4 o;
    o[0] = (__bf16)v.x; o[1] = (__bf16)v.y; o[2] = (__bf16)v.z; o[3] = (__bf16)v.w;
    *(bf16x4*)(xb + (size_t)t * 4) = o;
}

// ---------------------------------------------------------------------------
// Pack W[d][K][H] fp32 -> bf16 32x32x16 A-fragment order via LDS transpose.
// Frag layout (A = W^T, m = H-col, k = K-row): lane l holds
//   A[ct*32 + (l&31)][ks*16 + (l>>5)*8 + j],  j = 0..7
//   Wp[((d*16 + ct)*nks16 + ks)*512 + l*8 + j] = W[d][ks*16+(l>>5)*8+j][ct*32+(l&31)]
// ---------------------------------------------------------------------------
__global__ void pack_w(const float* __restrict__ W, __bf16* __restrict__ Wp, int nks32) {
    __shared__ __bf16 Ls[32 * PLD];
    const int d  = blockIdx.x / nks32;
    const int ks = blockIdx.x % nks32;      // 32-row slab index
    const int tid = threadIdx.x;
    const int nks16 = nks32 * 2;
    const float* src = W + ((size_t)(d * nks32 + ks) * 32) * HH;

#pragma unroll
    for (int it = 0; it < 16; ++it) {
        int e = (it * 256 + tid) * 4;
        float4 v = *(const float4*)(src + e);
        bf16x4 o;
        o[0] = (__bf16)v.x; o[1] = (__bf16)v.y; o[2] = (__bf16)v.z; o[3] = (__bf16)v.w;
        *(bf16x4*)(Ls + (e >> 9) * PLD + (e & 511)) = o;
    }
    __syncthreads();

#pragma unroll
    for (int it = 0; it < 8; ++it) {
        int u  = it * 256 + tid;            // [0, 2048): 8-elem output units
        int l  = u & 63;
        int ct = (u >> 6) & 15;             // 32-col tile
        int kh = u >> 10;                   // k-substep within slab (0,1)
        int lr = l & 31, lh = l >> 5;
        bf16x8 v;
#pragma unroll
        for (int j = 0; j < 8; ++j)
            v[j] = Ls[(kh * 16 + lh * 8 + j) * PLD + ct * 32 + lr];
        *(bf16x8*)(Wp + ((size_t)(d * 16 + ct) * nks16 + (ks * 2 + kh)) * 512 + l * 8) = v;
    }
}

// ---------------------------------------------------------------------------
// Fused per-(d, row-tile) MLP, 32x32x16 MFMA, transposed operand order.
// Round 4: CONVOY BREAKING. All waves previously ran the identical K-loop in
// lockstep -> correlated L2 burst stalls + matrix-pipe queueing (MfmaUtil
// pinned ~37% across r0-r3 regardless of structure). K-accumulation is
// commutative, so wave w starts its K-loop at a staggered offset (ks = 4w in
// phase 2, ks = w in phase 1), wrapping mod loop length: load/MFMA bursts of
// the 8 waves now interleave in time and hit different W addresses.
// Also: W2[d] (2KB) prefetched to LDS via global_load_lds during phase 1
// (removes phase-3 dependent global-latency tail).
// Hard gate: 64 VGPR + 64 AGPR acc = 128 regs = 4 waves/SIMD (r2 lesson).
// ---------------------------------------------------------------------------
__launch_bounds__(512, 4)
__global__ void grandag_main(const __bf16* __restrict__ xb,
                             const __bf16* __restrict__ W0p,
                             const __bf16* __restrict__ W1p,
                             const float* __restrict__ W2,
                             float* __restrict__ out) {
    __shared__ __bf16 h1s[NT * HH];      // 65536 B
    __shared__ float  outp2[8][NT];      // 2048 B: per-wave partials (no atomics)
    __shared__ float  w2s[HH];           // 2048 B: W2[d] staged by global_load_lds

    const int b  = blockIdx.x;
    // XCD swizzle: d % 8 == blockIdx % 8 -> all 32 tiles of a d on one XCD
    const int d  = ((b >> 8) << 3) | (b & 7);
    const int n0 = ((b >> 3) & 31) * NT;

    const int tid = threadIdx.x;
    const int wq  = __builtin_amdgcn_readfirstlane(tid >> 6);  // wave id (SGPR)
    const int l   = tid & 63;
    const int lr  = l & 31;     // C/D col = batch row within 32-tile
    const int lh  = l >> 5;     // k half-group
    const int swz = lr & 7;     // h1s chunk-swizzle key (row-derived)

    const int kz  = d >> 4;          // k-step containing column d of X
    const int lhz = (d >> 3) & 1;    // half-group containing it
    const int jz  = d & 7;           // element containing it

    // W2[d] -> LDS: waves 0,1 each DMA 1KB (16B/lane). Completed by the
    // phase-1 barrier's vmcnt drain; consumed in phase 3.
    if (wq < 2) {
        const float* g = W2 + (size_t)d * HH + (size_t)(wq * 64 + l) * 4;
        __builtin_amdgcn_global_load_lds((as1cv)g, (as3v)(w2s + wq * 256), 16, 0, 0);
    }

    // ---- phase 1: acc[mt][nt] = W0[d]^T (32-col tiles) . Xmask^T (32-row tiles)
    // staggered: wave w starts at k-step w (8 steps total)
    {
        floatx16 acc[2][2] = {};
        const __bf16* W0b = W0p + ((size_t)(d * 16 + wq * 2) * 8) * 512 + (size_t)l * 8;
        const __bf16* xbb = xb + (size_t)(n0 + lr) * DD + lh * 8;

        int ke = wq & 7;
        bf16x8 wa0 = *(const bf16x8*)(W0b + (size_t)ke * 512);
        bf16x8 wa1 = *(const bf16x8*)(W0b + (size_t)(8 + ke) * 512);
#pragma unroll
        for (int i = 0; i < 8; i++) {
            const int kn = (ke + 1) & 7;
            bf16x8 wb0 = *(const bf16x8*)(W0b + (size_t)kn * 512);
            bf16x8 wb1 = *(const bf16x8*)(W0b + (size_t)(8 + kn) * 512);
            bf16x8 x0 = *(const bf16x8*)(xbb + (size_t)ke * 16);
            bf16x8 x1 = *(const bf16x8*)(xbb + (size_t)(32 * DD) + ke * 16);
            if (ke == kz && lh == lhz) {
#pragma unroll
                for (int j = 0; j < 8; j++)
                    if (j == jz) { x0[j] = (__bf16)0.f; x1[j] = (__bf16)0.f; }
            }
            acc[0][0] = __builtin_amdgcn_mfma_f32_32x32x16_bf16(wa0, x0, acc[0][0], 0, 0, 0);
            acc[0][1] = __builtin_amdgcn_mfma_f32_32x32x16_bf16(wa0, x1, acc[0][1], 0, 0, 0);
            acc[1][0] = __builtin_amdgcn_mfma_f32_32x32x16_bf16(wa1, x0, acc[1][0], 0, 0, 0);
            acc[1][1] = __builtin_amdgcn_mfma_f32_32x32x16_bf16(wa1, x1, acc[1][1], 0, 0, 0);
            wa0 = wb0; wa1 = wb1; ke = kn;
        }
        // epilogue: lane holds h1[row = nt*32+lr][hcol = 64w+32mt+8q2+4lh+i]
        // h1s layout: row-major 512, 16B chunks XOR-swizzled by row&7.
#pragma unroll
        for (int mt = 0; mt < 2; mt++) {
#pragma unroll
            for (int q2 = 0; q2 < 4; q2++) {
                const int chunk = 8 * wq + 4 * mt + q2;
#pragma unroll
                for (int nt = 0; nt < 2; nt++) {
                    const int row = nt * 32 + lr;
                    bf16x4 o;
#pragma unroll
                    for (int i = 0; i < 4; i++) {
                        float v = acc[mt][nt][q2 * 4 + i];
                        o[i] = (__bf16)fmaxf(v, 0.01f * v);   // leaky relu
                    }
                    *(bf16x4*)(h1s + (size_t)row * HH + ((chunk ^ swz) << 3) + 4 * lh) = o;
                }
            }
        }
    }
    __syncthreads();

    // ---- phase 2: acc2[mt][nt] = W1[d]^T (32-col tiles) . h1^T (32-row tiles)
    // staggered: wave w starts at k-step 4w of 32, wrapping (commutative sum)
    floatx16 acc2[2][2] = {};
    {
        const __bf16* W1b  = W1p + ((size_t)(d * 16 + wq * 2) * 32) * 512 + (size_t)l * 8;
        const __bf16* h1b0 = h1s + (size_t)lr * HH;          // nt=0 row
        const __bf16* h1b1 = h1s + (size_t)(32 + lr) * HH;   // nt=1 row

        int ke = (wq * 4) & 31;
        bf16x8 wa0 = *(const bf16x8*)(W1b + (size_t)ke * 512);
        bf16x8 wa1 = *(const bf16x8*)(W1b + (size_t)(32 + ke) * 512);
#pragma unroll
        for (int i = 0; i < 32; i++) {
            const int kn = (ke + 1) & 31;
            bf16x8 wb0 = *(const bf16x8*)(W1b + (size_t)kn * 512);
            bf16x8 wb1 = *(const bf16x8*)(W1b + (size_t)(32 + kn) * 512);
            const int hoff = ((2 * ke + lh) ^ swz) << 3;
            bf16x8 h0  = *(const bf16x8*)(h1b0 + hoff);
            bf16x8 h1v = *(const bf16x8*)(h1b1 + hoff);
            acc2[0][0] = __builtin_amdgcn_mfma_f32_32x32x16_bf16(wa0, h0,  acc2[0][0], 0, 0, 0);
            acc2[0][1] = __builtin_amdgcn_mfma_f32_32x32x16_bf16(wa0, h1v, acc2[0][1], 0, 0, 0);
            acc2[1][0] = __builtin_amdgcn_mfma_f32_32x32x16_bf16(wa1, h0,  acc2[1][0], 0, 0, 0);
            acc2[1][1] = __builtin_amdgcn_mfma_f32_32x32x16_bf16(wa1, h1v, acc2[1][1], 0, 0, 0);
            wa0 = wb0; wa1 = wb1; ke = kn;
        }
    }

    // ---- phase 3: out = leaky(h2) @ W2[d] (from LDS); lane lr holds rows nt*32+lr
    {
        const float* W2b = w2s + wq * 64 + lh * 4;
#pragma unroll
        for (int nt = 0; nt < 2; nt++) {
            float s = 0.f;
#pragma unroll
            for (int mt = 0; mt < 2; mt++) {
#pragma unroll
                for (int q2 = 0; q2 < 4; q2++) {
                    floatx4 w2q = *(const floatx4*)(W2b + mt * 32 + 8 * q2);
#pragma unroll
                    for (int i = 0; i < 4; i++) {
                        float v = acc2[mt][nt][q2 * 4 + i];
                        s += fmaxf(v, 0.01f * v) * w2q[i];
                    }
                }
            }
            // the lh=1 half holds the other 32 h-cols of this wave
            s += __shfl_xor(s, 32, 64);
            if (!lh) outp2[wq][nt * 32 + lr] = s;   // per-wave partial, no atomics
        }
    }
    __syncthreads();
    if (tid < NT) {
        float v = 0.f;
#pragma unroll
        for (int ww = 0; ww < 8; ww++) v += outp2[ww][tid];
        out[(size_t)(n0 + tid) * DD + d] = v;
    }
}

// ---------------------------------------------------------------------------
extern "C" void kernel_launch(void* const* d_in, const int* in_sizes, int n_in,
                              void* d_out, int out_size, void* d_ws, size_t ws_size,
                              hipStream_t stream) {
    const float* x  = (const float*)d_in[0];
    const float* W0 = (const float*)d_in[1];
    const float* W1 = (const float*)d_in[2];
    const float* W2 = (const float*)d_in[3];
    float* out = (float*)d_out;

    __bf16* W0p = (__bf16*)d_ws;                                          // 16.8 MB
    __bf16* W1p = (__bf16*)((char*)d_ws + (size_t)DD * DD * HH * 2);      // 67.1 MB
    __bf16* xb  = (__bf16*)((char*)d_ws + (size_t)DD * DD * HH * 2
                                        + (size_t)DD * HH * HH * 2);      // 0.5 MB

    cvt_x<<<dim3(NN * DD / (256 * 4)), 256, 0, stream>>>(x, xb);
    pack_w<<<dim3(DD * (DD / 32)), 256, 0, stream>>>(W0, W0p, DD / 32);   // 512 blocks
    pack_w<<<dim3(DD * (HH / 32)), 256, 0, stream>>>(W1, W1p, HH / 32);   // 2048 blocks

    grandag_main<<<dim3(DD * (NN / NT)), 512, 0, stream>>>(xb, W0p, W1p, W2, out);
}